// Round 6
// baseline (178.563 us; speedup 1.0000x reference)
//
#include <hip/hip_runtime.h>

// VQ: x [B=64, D=64, H=32, W=32] fp32, E [D=64, K=1024] fp32.
// flat rows N = B*H*W = 65536 over (b, h, w) order.
// d_out (float32): [0,4194304) quantized [B,D,H,W]; [4194304] dict_loss;
//   [4194305] commit_loss; [4194306,+65536) indices as floats.
//
// Round-6: lane = row, wave = 8-k slice, and x held in 64 VGPRs.
//   Main loop has ZERO LDS ops: 512 v_fmac (VGPR x SGPR) + uniform s_loads of
//   E per kt-iter. x staged once via global_load_lds (epilogue reuses LDS copy),
//   then hoisted to registers with fully-static indexing (no scratch).

#define DDIM 64
#define KNUM 1024
#define HWN  1024
#define ROWS_PER_BLOCK 64

typedef __attribute__((ext_vector_type(8))) float float8v;

__global__ __launch_bounds__(256) void vq_esq_kernel(const float* __restrict__ E,
                                                     float* __restrict__ esq) {
    int k = blockIdx.x * 256 + threadIdx.x;  // 4 blocks x 256 = 1024
    float s = 0.f;
    #pragma unroll 8
    for (int d = 0; d < DDIM; ++d) {
        float e = E[d * KNUM + k];
        s = fmaf(e, e, s);
    }
    esq[k] = s;
}

__global__ __launch_bounds__(256, 4) void vq_main_kernel(const float* __restrict__ x,
                                                         const float* __restrict__ E,
                                                         const float* __restrict__ esq,
                                                         float* __restrict__ out_q,
                                                         float* __restrict__ out_idx,
                                                         float* __restrict__ partial) {
    __shared__ float xlds[DDIM * ROWS_PER_BLOCK];  // [d][row] 16 KB
    __shared__ float bdls[4 * ROWS_PER_BLOCK];     // per-wave row winners (dist)
    __shared__ int   bkls[4 * ROWS_PER_BLOCK];     // per-wave row winners (k)
    __shared__ int   klds[ROWS_PER_BLOCK];
    __shared__ float redlds[4];

    const int t  = threadIdx.x;
    const int wv = t >> 6;        // wave 0..3
    const int ln = t & 63;        // lane = row
    const int n0 = blockIdx.x * ROWS_PER_BLOCK;
    const int b   = n0 >> 10;
    const int hw0 = n0 & 1023;
    const float* xbase = x + (size_t)b * (DDIM * HWN) + hw0;

    // ---- stage x tile [64 d][64 rows] via global_load_lds (16B), linear ----
    #pragma unroll
    for (int it = 0; it < 4; ++it) {
        int dbase = it * 16 + wv * 4;
        int dsub  = ln >> 4;
        int off   = (ln & 15) * 4;
        const float* g = xbase + (dbase + dsub) * HWN + off;
        __builtin_amdgcn_global_load_lds(
            (const __attribute__((address_space(1))) void*)g,
            (__attribute__((address_space(3))) void*)&xlds[dbase * 64 + ln * 4],
            16, 0, 0);
    }
    __syncthreads();

    // ---- hoist this lane's row into registers (static indices only) ----
    float x_r[DDIM];
    #pragma unroll
    for (int d = 0; d < DDIM; ++d)
        x_r[d] = xlds[d * 64 + ln];   // ds_read_b32, base=ln*4, imm offset d*256

    const int wvu = __builtin_amdgcn_readfirstlane(wv);  // wave-uniform

    float best  = 3.4e38f;
    int   bestk = 0;

    // 32 k-iters; wave wv covers k = kt*32 + wvu*8 .. +7 each iter.
    for (int kt = 0; kt < 32; ++kt) {
        const int kbase = kt * 32 + wvu * 8;
        const float* ep = E + kbase;

        float s[8];
        #pragma unroll
        for (int m = 0; m < 8; ++m) s[m] = 0.f;

        #pragma unroll
        for (int d = 0; d < DDIM; ++d) {
            float8v ee = *reinterpret_cast<const float8v*>(ep + d * KNUM);  // uniform -> s_load
            #pragma unroll
            for (int m = 0; m < 8; ++m)
                s[m] = fmaf(x_r[d], ee[m], s[m]);
        }

        float8v eq = *reinterpret_cast<const float8v*>(esq + kbase);
        #pragma unroll
        for (int m = 0; m < 8; ++m) {
            float dist = fmaf(-2.f, s[m], eq[m]);   // |e|^2 - 2 x.e  (|x|^2 const per row)
            int   k    = kbase + m;
            if (dist < best) { best = dist; bestk = k; }   // m,kt ascending -> first-min
        }
    }

    bdls[wv * 64 + ln] = best;
    bkls[wv * 64 + ln] = bestk;
    __syncthreads();

    // cross-wave merge: thread t<64 owns row t (lexicographic (dist, k) min)
    if (t < ROWS_PER_BLOCK) {
        float bd = bdls[t]; int bk = bkls[t];
        #pragma unroll
        for (int w = 1; w < 4; ++w) {
            float od = bdls[w * 64 + t]; int ok = bkls[w * 64 + t];
            if (od < bd || (od == bd && ok < bk)) { bd = od; bk = ok; }
        }
        klds[t] = bk;
        out_idx[n0 + t] = (float)bk;
    }
    __syncthreads();

    // epilogue: gather E columns, write quantized coalesced, loss partial
    float lsum = 0.f;
    float* outbase = out_q + (size_t)b * (DDIM * HWN) + hw0;
    #pragma unroll 4
    for (int it = 0; it < 16; ++it) {
        int d = it * 4 + (t >> 6);
        int r = t & 63;
        int k = klds[r];
        float q  = E[d * KNUM + k];
        float xv = xlds[d * 64 + r];
        float diff = xv - q;
        lsum = fmaf(diff, diff, lsum);
        outbase[d * HWN + r] = q;
    }

    #pragma unroll
    for (int off = 32; off >= 1; off >>= 1)
        lsum += __shfl_xor(lsum, off);
    if ((t & 63) == 0) redlds[t >> 6] = lsum;
    __syncthreads();
    if (t == 0)
        partial[blockIdx.x] = (redlds[0] + redlds[1]) + (redlds[2] + redlds[3]);
}

__global__ __launch_bounds__(256) void vq_loss_kernel(const float* __restrict__ partial,
                                                      float* __restrict__ out_loss) {
    __shared__ float red[4];
    int t = threadIdx.x;
    float s = 0.f;
    #pragma unroll
    for (int it = 0; it < 4; ++it) s += partial[it * 256 + t];
    #pragma unroll
    for (int off = 32; off >= 1; off >>= 1) s += __shfl_xor(s, off);
    if ((t & 63) == 0) red[t >> 6] = s;
    __syncthreads();
    if (t == 0) {
        float loss = ((red[0] + red[1]) + (red[2] + red[3])) / 4194304.f;
        out_loss[0] = loss;   // dictionary_loss
        out_loss[1] = loss;   // commitment_loss (numerically identical)
    }
}

extern "C" void kernel_launch(void* const* d_in, const int* in_sizes, int n_in,
                              void* d_out, int out_size, void* d_ws, size_t ws_size,
                              hipStream_t stream) {
    const float* x = (const float*)d_in[0];
    const float* E = (const float*)d_in[1];
    float* out      = (float*)d_out;
    float* out_q    = out;             // 4194304
    float* out_loss = out + 4194304;   // 2 scalars
    float* out_idx  = out + 4194306;   // 65536 indices (as float)
    float* esq      = (float*)d_ws;    // 1024 floats
    float* partial  = esq + 1024;      // 1024 floats

    vq_esq_kernel<<<4, 256, 0, stream>>>(E, esq);
    vq_main_kernel<<<1024, 256, 0, stream>>>(x, E, esq, out_q, out_idx, partial);
    vq_loss_kernel<<<1, 256, 0, stream>>>(partial, out_loss);
}

// Round 7
// 113.541 us; speedup vs baseline: 1.5727x; 1.5727x over previous
//
#include <hip/hip_runtime.h>

// VQ: x [B=64, D=64, H=32, W=32] fp32, E [D=64, K=1024] fp32.
// flat rows N = B*H*W = 65536 over (b, h, w) order.
// d_out (float32): [0,4194304) quantized [B,D,H,W]; [4194304] dict_loss;
//   [4194305] commit_loss; [4194306,+65536) indices as floats.
//
// Round-7: lane = row, wave = 32-k slice (widened from 8), E via uniform
// s_load from L2 (round-5 proven path, VGPR=20 there). 8 kt-iters; per-thread
// x LDS reads drop 2048 -> 512 so the LDS pipe (47k cyc/CU) is well under the
// VALU window (131k). 32 independent acc chains hide s_load latency.

#define DDIM 64
#define KNUM 1024
#define HWN  1024
#define ROWS_PER_BLOCK 64

typedef __attribute__((ext_vector_type(8))) float float8v;

__global__ __launch_bounds__(256) void vq_esq_kernel(const float* __restrict__ E,
                                                     float* __restrict__ esq) {
    int k = blockIdx.x * 256 + threadIdx.x;  // 4 blocks x 256 = 1024
    float s = 0.f;
    #pragma unroll 8
    for (int d = 0; d < DDIM; ++d) {
        float e = E[d * KNUM + k];
        s = fmaf(e, e, s);
    }
    esq[k] = s;
}

__global__ __launch_bounds__(256, 4) void vq_main_kernel(const float* __restrict__ x,
                                                         const float* __restrict__ E,
                                                         const float* __restrict__ esq,
                                                         float* __restrict__ out_q,
                                                         float* __restrict__ out_idx,
                                                         float* __restrict__ partial) {
    __shared__ float xlds[DDIM * ROWS_PER_BLOCK];  // [d][row] 16 KB
    __shared__ float bdls[4 * ROWS_PER_BLOCK];     // per-wave row winners (dist)
    __shared__ int   bkls[4 * ROWS_PER_BLOCK];     // per-wave row winners (k)
    __shared__ int   klds[ROWS_PER_BLOCK];
    __shared__ float redlds[4];

    const int t  = threadIdx.x;
    const int wv = t >> 6;        // wave 0..3
    const int ln = t & 63;        // lane = row
    const int n0 = blockIdx.x * ROWS_PER_BLOCK;
    const int b   = n0 >> 10;
    const int hw0 = n0 & 1023;
    const float* xbase = x + (size_t)b * (DDIM * HWN) + hw0;

    // ---- stage x tile [64 d][64 rows] via global_load_lds (16B), linear ----
    #pragma unroll
    for (int it = 0; it < 4; ++it) {
        int dbase = it * 16 + wv * 4;
        int dsub  = ln >> 4;
        int off   = (ln & 15) * 4;
        const float* g = xbase + (dbase + dsub) * HWN + off;
        __builtin_amdgcn_global_load_lds(
            (const __attribute__((address_space(1))) void*)g,
            (__attribute__((address_space(3))) void*)&xlds[dbase * 64 + ln * 4],
            16, 0, 0);
    }
    __syncthreads();

    const int wvu = __builtin_amdgcn_readfirstlane(wv);  // wave-uniform

    float best  = 3.4e38f;
    int   bestk = 0;

    // 8 kt-iters; wave wv covers k = kt*128 + wvu*32 .. +31 each iter.
    for (int kt = 0; kt < 8; ++kt) {
        const int kbase = kt * 128 + wvu * 32;
        const float* ep = E + kbase;

        float s[32];
        #pragma unroll
        for (int m = 0; m < 32; ++m) s[m] = 0.f;

        #pragma unroll 4
        for (int d = 0; d < DDIM; ++d) {
            float xv = xlds[d * 64 + ln];   // stride-1 b32 (2-way alias = free)
            float8v e0 = *reinterpret_cast<const float8v*>(ep + d * KNUM);       // uniform
            float8v e1 = *reinterpret_cast<const float8v*>(ep + d * KNUM + 8);   //  -> s_load
            float8v e2 = *reinterpret_cast<const float8v*>(ep + d * KNUM + 16);
            float8v e3 = *reinterpret_cast<const float8v*>(ep + d * KNUM + 24);
            #pragma unroll
            for (int m = 0; m < 8; ++m) {
                s[m]      = fmaf(xv, e0[m], s[m]);
                s[m + 8]  = fmaf(xv, e1[m], s[m + 8]);
                s[m + 16] = fmaf(xv, e2[m], s[m + 16]);
                s[m + 24] = fmaf(xv, e3[m], s[m + 24]);
            }
        }

        float8v q0 = *reinterpret_cast<const float8v*>(esq + kbase);
        float8v q1 = *reinterpret_cast<const float8v*>(esq + kbase + 8);
        float8v q2 = *reinterpret_cast<const float8v*>(esq + kbase + 16);
        float8v q3 = *reinterpret_cast<const float8v*>(esq + kbase + 24);
        #pragma unroll
        for (int m = 0; m < 32; ++m) {
            float eqv = (m < 8) ? q0[m & 7] : (m < 16) ? q1[m & 7]
                       : (m < 24) ? q2[m & 7] : q3[m & 7];
            float dist = fmaf(-2.f, s[m], eqv);   // |e|^2 - 2 x.e  (|x|^2 const per row)
            int   k    = kbase + m;
            if (dist < best) { best = dist; bestk = k; }   // m,kt ascending -> first-min
        }
    }

    bdls[wv * 64 + ln] = best;
    bkls[wv * 64 + ln] = bestk;
    __syncthreads();

    // cross-wave merge: thread t<64 owns row t (lexicographic (dist, k) min)
    if (t < ROWS_PER_BLOCK) {
        float bd = bdls[t]; int bk = bkls[t];
        #pragma unroll
        for (int w = 1; w < 4; ++w) {
            float od = bdls[w * 64 + t]; int ok = bkls[w * 64 + t];
            if (od < bd || (od == bd && ok < bk)) { bd = od; bk = ok; }
        }
        klds[t] = bk;
        out_idx[n0 + t] = (float)bk;
    }
    __syncthreads();

    // epilogue: gather E columns, write quantized coalesced, loss partial
    float lsum = 0.f;
    float* outbase = out_q + (size_t)b * (DDIM * HWN) + hw0;
    #pragma unroll 4
    for (int it = 0; it < 16; ++it) {
        int d = it * 4 + (t >> 6);
        int r = t & 63;
        int k = klds[r];
        float q  = E[d * KNUM + k];
        float xv = xlds[d * 64 + r];
        float diff = xv - q;
        lsum = fmaf(diff, diff, lsum);
        outbase[d * HWN + r] = q;
    }

    #pragma unroll
    for (int off = 32; off >= 1; off >>= 1)
        lsum += __shfl_xor(lsum, off);
    if ((t & 63) == 0) redlds[t >> 6] = lsum;
    __syncthreads();
    if (t == 0)
        partial[blockIdx.x] = (redlds[0] + redlds[1]) + (redlds[2] + redlds[3]);
}

__global__ __launch_bounds__(256) void vq_loss_kernel(const float* __restrict__ partial,
                                                      float* __restrict__ out_loss) {
    __shared__ float red[4];
    int t = threadIdx.x;
    float s = 0.f;
    #pragma unroll
    for (int it = 0; it < 4; ++it) s += partial[it * 256 + t];
    #pragma unroll
    for (int off = 32; off >= 1; off >>= 1) s += __shfl_xor(s, off);
    if ((t & 63) == 0) red[t >> 6] = s;
    __syncthreads();
    if (t == 0) {
        float loss = ((red[0] + red[1]) + (red[2] + red[3])) / 4194304.f;
        out_loss[0] = loss;   // dictionary_loss
        out_loss[1] = loss;   // commitment_loss (numerically identical)
    }
}

extern "C" void kernel_launch(void* const* d_in, const int* in_sizes, int n_in,
                              void* d_out, int out_size, void* d_ws, size_t ws_size,
                              hipStream_t stream) {
    const float* x = (const float*)d_in[0];
    const float* E = (const float*)d_in[1];
    float* out      = (float*)d_out;
    float* out_q    = out;             // 4194304
    float* out_loss = out + 4194304;   // 2 scalars
    float* out_idx  = out + 4194306;   // 65536 indices (as float)
    float* esq      = (float*)d_ws;    // 1024 floats
    float* partial  = esq + 1024;      // 1024 floats

    vq_esq_kernel<<<4, 256, 0, stream>>>(E, esq);
    vq_main_kernel<<<1024, 256, 0, stream>>>(x, E, esq, out_q, out_idx, partial);
    vq_loss_kernel<<<1, 256, 0, stream>>>(partial, out_loss);
}